// Round 5
// baseline (184.753 us; speedup 1.0000x reference)
//
#include <hip/hip_runtime.h>
#include <math.h>

// Modulated deformable conv v2: B=4, C=256, H=W=64, O=256, K=3, PAD=1
// r23: K3 -> register-direct, BARRIER-FREE deform GEMM. The B-fragment for
//      mfma 16x16x32 in lane (pos=l15, g) is channels [8g,8g+8) of the
//      K-slice = one contiguous dwordx4 of the NHWC bf16 plane. So each lane
//      gathers its own 4 corners, combines bilinear+mask in registers, and
//      feeds MFMA straight from VGPRs: no cols LDS, no ds_write/ds_read, no
//      per-chunk barriers. 8 waves = 2 out-halves x 4 pos-tiles.
//      K1 nhwcpack, K2 offmask_mfma verbatim; 3-kernel launch (fusion hurt).

constexpr int Bn = 4;
constexpr int Cn = 256;
constexpr int Hn = 64;
constexpr int Wn = 64;
constexpr int On = 256;
constexpr int PB = Hn * Wn;     // 4096
constexpr int NCH = 27;

typedef __attribute__((ext_vector_type(8))) short bf16x8;  // 8 bf16 (4 VGPRs)
typedef __attribute__((ext_vector_type(4))) float f32x4;
typedef __attribute__((ext_vector_type(2))) float f32x2;
typedef __attribute__((ext_vector_type(4))) uint  uint4v;

union FragU { uint4 u; bf16x8 h; };

__device__ inline ushort f2bf(float f) {
    uint u = __builtin_bit_cast(uint, f);
    return (ushort)((u + 0x7fffu + ((u >> 16) & 1u)) >> 16);
}
__device__ inline float bf2f(ushort h) {
    uint u = (uint)h << 16;
    return __builtin_bit_cast(float, u);
}
__device__ inline float bflo(uint u) { u <<= 16;          return __builtin_bit_cast(float, u); }
__device__ inline float bfhi(uint u) { u &= 0xffff0000u;  return __builtin_bit_cast(float, u); }
__device__ inline f32x2 unpk2(uint u) { return (f32x2){bflo(u), bfhi(u)}; }

// ---------------------------------------------------------------- kernel 1
// (r16/r17-proven) NCHW fp32 -> NHWC bf16 hi/lo planes + weight packing.
__global__ __launch_bounds__(256)
void nhwcpack_kernel(const float* __restrict__ x,
                     const float* __restrict__ w,
                     const float* __restrict__ offw,
                     const float* __restrict__ modw,
                     ushort* __restrict__ xbf, ushort* __restrict__ xlr,
                     ushort* __restrict__ wTb,
                     ushort* __restrict__ owh, ushort* __restrict__ owl)
{
    const int bid = blockIdx.x;
    const int b = bid >> 7, seg = bid & 127;
    const int t = threadIdx.x;
    __shared__ float tile[32][257];

    const float* src = x + (size_t)b * Cn * PB + seg * 32;
    #pragma unroll 4
    for (int i = 0; i < 32; ++i) {
        const int idx = i * 256 + t;
        const int c = idx >> 5, p = idx & 31;
        tile[p][c] = src[(size_t)c * PB + p];
    }
    __syncthreads();

    const int pr = t & 127;
    const int r0 = (t >> 7) * 16;
    uint* dH = reinterpret_cast<uint*>(xbf + ((size_t)b * PB + seg * 32) * 256);
    uint* dL = reinterpret_cast<uint*>(xlr + ((size_t)b * PB + seg * 32) * 256);
    #pragma unroll 4
    for (int i = 0; i < 16; ++i) {
        const int row = r0 + i;
        const float v0 = tile[row][2 * pr];
        const float v1 = tile[row][2 * pr + 1];
        const ushort h0 = f2bf(v0), h1 = f2bf(v1);
        const ushort l0 = f2bf(v0 - bf2f(h0));
        const ushort l1 = f2bf(v1 - bf2f(h1));
        dH[(size_t)row * 128 + pr] = (uint)h0 | ((uint)h1 << 16);
        dL[(size_t)row * 128 + pr] = (uint)l0 | ((uint)l1 << 16);
    }

    #pragma unroll 1
    for (int u = 0; u < 5; ++u) {
        int unit = (u < 4) ? bid * 4 + u : (bid < 256 ? 2048 + bid : -1);
        if (unit < 0) break;
        const int tap = unit >> 8, c = unit & 255;
        const int o = t;
        wTb[((size_t)(unit >> 3) * 256 + o) * 8 + (c & 7)] =
            f2bf(w[((size_t)o * Cn + c) * 9 + tap]);
        if (o < 32) {
            float v = 0.f;
            if (o < 18)      v = offw[((size_t)o * Cn + c) * 9 + tap];
            else if (o < 27) v = modw[((size_t)(o - 18) * Cn + c) * 9 + tap];
            const ushort h = f2bf(v);
            const ushort l = f2bf(v - bf2f(h));
            const size_t base = ((size_t)(unit >> 3) * 32 + o) * 8 + (c & 7);
            owh[base] = h;
            owl[base] = l;
        }
    }
}

// ---------------------------------------------------------------- kernel 2
// (r13-proven, verbatim) offset/mask conv via split-bf16 MFMA -> offm global.
__global__ __launch_bounds__(512, 2)
void offmask_mfma_kernel(const ushort* __restrict__ xbf,
                         const ushort* __restrict__ xlr,
                         const float* __restrict__ offb,
                         const float* __restrict__ modb,
                         const ushort* __restrict__ owh,
                         const ushort* __restrict__ owl,
                         float* __restrict__ offm)
{
    const int hw = blockIdx.x;
    const int blk = (hw & 7) * 32 + (hw >> 3);
    const int b = blk >> 6, row = blk & 63;
    const int t = threadIdx.x;
    const int lane = t & 63;
    const int wv  = t >> 6;
    const int l15 = lane & 15;
    const int g   = lane >> 4;
    const int mt  = wv >> 2;
    const int nt  = wv & 3;

    __shared__ uint colsH[8][1024];
    __shared__ uint colsL[8][1024];

    const ushort* xhb = xbf + (size_t)b * PB * 256;
    const ushort* xlb = xlr + (size_t)b * PB * 256;
    const int posT0 = t >> 4;
    const int chq   = t & 15;

    const int ws0 = posT0 * 16
        + 4 * ((chq >> 2) ^ (posT0 & 3) ^ ((posT0 >> 2) & 3)) + (chq & 3);
    const int posT1 = posT0 + 32;
    const int ws1 = posT1 * 16
        + 4 * ((chq >> 2) ^ (posT1 & 3) ^ ((posT1 >> 2) & 3)) + (chq & 3);

    const uint4* owhV = reinterpret_cast<const uint4*>(owh);
    const uint4* owlV = reinterpret_cast<const uint4*>(owl);

    f32x4 acc = (f32x4){0.f, 0.f, 0.f, 0.f};
    const int p = nt * 16 + l15;
    const int ridx = p * 4 + (g ^ (p & 3) ^ ((p >> 2) & 3));

    #pragma unroll 1
    for (int tap = 0; tap < 9; ++tap) {
        const int ty = tap / 3, tx = tap % 3;
        const int y = row - 1 + ty;
        const int xc0 = posT0 - 1 + tx;
        const int xc1 = posT1 - 1 + tx;
        const bool ok0 = (y >= 0) && (y < Hn) && (xc0 >= 0) && (xc0 < Wn);
        const bool ok1 = (y >= 0) && (y < Hn) && (xc1 >= 0) && (xc1 < Wn);
        const int ya  = max(y, 0);
        const int xa0 = min(max(xc0, 0), Wn - 1);
        const int xa1 = min(max(xc1, 0), Wn - 1);
        const size_t p0b = ((size_t)(ya * Wn + xa0)) * 256 + 2 * chq;
        const size_t p1b = ((size_t)(ya * Wn + xa1)) * 256 + 2 * chq;

        uint h0[8], l0[8], h1[8], l1[8];
        #pragma unroll
        for (int s = 0; s < 8; ++s) {
            h0[s] = l0[s] = h1[s] = l1[s] = 0u;
            if (ok0) {
                h0[s] = *reinterpret_cast<const uint*>(xhb + p0b + s * 32);
                l0[s] = *reinterpret_cast<const uint*>(xlb + p0b + s * 32);
            }
            if (ok1) {
                h1[s] = *reinterpret_cast<const uint*>(xhb + p1b + s * 32);
                l1[s] = *reinterpret_cast<const uint*>(xlb + p1b + s * 32);
            }
        }
        uint4 aH[8], aL[8];
        #pragma unroll
        for (int s = 0; s < 8; ++s) {
            const size_t kb = (size_t)((tap * 8 + s) * 4 + g) * 32 + mt * 16 + l15;
            aH[s] = owhV[kb];
            aL[s] = owlV[kb];
        }

        __syncthreads();

        #pragma unroll
        for (int s = 0; s < 8; ++s) {
            colsH[s][ws0] = h0[s];
            colsL[s][ws0] = l0[s];
            colsH[s][ws1] = h1[s];
            colsL[s][ws1] = l1[s];
        }
        __syncthreads();

        #pragma unroll
        for (int s = 0; s < 8; ++s) {
            FragU aHH, aLL, bH, bL;
            aHH.u = aH[s]; aLL.u = aL[s];
            bH.u = reinterpret_cast<const uint4*>(colsH[s])[ridx];
            bL.u = reinterpret_cast<const uint4*>(colsL[s])[ridx];
            acc = __builtin_amdgcn_mfma_f32_16x16x32_bf16(aHH.h, bH.h, acc, 0, 0, 0);
            acc = __builtin_amdgcn_mfma_f32_16x16x32_bf16(aHH.h, bL.h, acc, 0, 0, 0);
            acc = __builtin_amdgcn_mfma_f32_16x16x32_bf16(aLL.h, bH.h, acc, 0, 0, 0);
        }
    }

    const int pos = nt * 16 + l15;
    #pragma unroll
    for (int j = 0; j < 4; ++j) {
        const int ch = mt * 16 + g * 4 + j;
        if (ch < NCH) {
            float v = acc[j];
            if (ch < 18) v += offb[ch];
            else         v = 2.f / (1.f + expf(-(v + modb[ch - 18])));
            offm[((size_t)(b * NCH + ch)) * PB + row * 64 + pos] = v;
        }
    }
}

// ---------------------------------------------------------------- kernel 3
// r23: register-direct deform GEMM. grid 256 = (b,row) XCD-swizzled.
// 512 threads = 8 waves = 2 out-halves (128 out) x 4 pos-tiles (16 pos).
// Lane (l15=pos-in-tile, g=k-octet). Per (tap, half, slice s):
//   - 4 corner gathers: dwordx4 at xb[off*256 + half*128 + s*32 + 8g]
//     == B-frag channels [8g,8g+8) of the K=32 slice (verified mapping)
//   - A: 8 dwordx4 from wTb (identical indices to r18's apre)
//   - packed f32x2 bilinear combine + v_cvt_pk_bf16_f32 -> B-frag in regs
//   - 8 MFMAs into acc[8]
// NO main-loop barriers, NO cols LDS. Only tap tables in LDS.
__global__ __launch_bounds__(512, 2)
void deform_reg_kernel(const ushort* __restrict__ xbf,
                       const float* __restrict__ offm,
                       const ushort* __restrict__ wTb,
                       float* __restrict__ out)
{
    const int hw = blockIdx.x;
    const int blk = (hw & 7) * 32 + (hw >> 3);   // XCD swizzle (256 = 8*32)
    const int b = blk >> 6, row = blk & 63;
    const int p0 = row * 64;
    const int t = threadIdx.x;
    const int lane = t & 63;
    const int wv  = t >> 6;
    const int l15 = lane & 15;
    const int g   = lane >> 4;
    const int wout = wv >> 2;          // 0..1 : out-half
    const int wpos = wv & 3;           // 0..3 : pos-tile
    const int p    = wpos * 16 + l15;  // my position within row (0..63)
    const int o0   = wout * 128;

    __shared__ int4   s_off[576];      // [tap][pos 0..63]
    __shared__ float4 s_wgt[576];

    for (int ti = t; ti < 576; ti += 512) {
        const int k = ti >> 6, pos = ti & 63;
        const int pp = p0 + pos;
        const float dy = offm[((size_t)(b * NCH + 2 * k)) * PB + pp];
        const float dx = offm[((size_t)(b * NCH + 2 * k + 1)) * PB + pp];
        const float m  = offm[((size_t)(b * NCH + 18 + k)) * PB + pp];
        const int ky = k / 3, kx = k % 3;
        const float py = dy + (float)(ky + row - 1);
        const float px = dx + (float)(kx + pos - 1);
        const float y0f = floorf(py), x0f = floorf(px);
        const float fy = py - y0f, fx = px - x0f;
        const int y0 = (int)y0f, x0i = (int)x0f;
        const int y1 = y0 + 1, x1 = x0i + 1;
        const bool vy0 = (y0 >= 0) && (y0 < Hn);
        const bool vy1 = (y1 >= 0) && (y1 < Hn);
        const bool vx0 = (x0i >= 0) && (x0i < Wn);
        const bool vx1 = (x1 >= 0) && (x1 < Wn);
        const int y0c = min(max(y0, 0), Hn - 1);
        const int y1c = min(max(y1, 0), Hn - 1);
        const int x0c = min(max(x0i, 0), Wn - 1);
        const int x1c = min(max(x1, 0), Wn - 1);
        s_off[ti] = make_int4(y0c * Wn + x0c, y0c * Wn + x1c,
                              y1c * Wn + x0c, y1c * Wn + x1c);
        s_wgt[ti] = make_float4(
            (vy0 && vx0) ? (1.f - fy) * (1.f - fx) * m : 0.f,
            (vy0 && vx1) ? (1.f - fy) * fx * m : 0.f,
            (vy1 && vx0) ? fy * (1.f - fx) * m : 0.f,
            (vy1 && vx1) ? fy * fx * m : 0.f);
    }
    __syncthreads();   // tap tables visible; the ONLY barrier

    const ushort* xb = xbf + (size_t)b * PB * 256;
    const uint4* wvp = reinterpret_cast<const uint4*>(wTb);

    f32x4 acc[8];
    #pragma unroll
    for (int i = 0; i < 8; ++i) acc[i] = (f32x4){0.f, 0.f, 0.f, 0.f};

    #pragma unroll 1
    for (int tap = 0; tap < 9; ++tap) {
        const int4   of = s_off[tap * 64 + p];
        const float4 wg = s_wgt[tap * 64 + p];
        // per-corner base pointers (channel octet 8g); inner offsets fold to
        // compile-time immediates.
        const ushort* cp0 = xb + (size_t)of.x * 256 + 8 * g;
        const ushort* cp1 = xb + (size_t)of.y * 256 + 8 * g;
        const ushort* cp2 = xb + (size_t)of.z * 256 + 8 * g;
        const ushort* cp3 = xb + (size_t)of.w * 256 + 8 * g;

        #pragma unroll 1
        for (int half = 0; half < 2; ++half) {
            const int cb = half * 128;
            const int kb0 = ((tap * 2 + half) * 4) * 4 + g;
            #pragma unroll
            for (int s = 0; s < 4; ++s) {
                const int co = cb + s * 32;
                const uint4v qa = *reinterpret_cast<const uint4v*>(cp0 + co);
                const uint4v qb = *reinterpret_cast<const uint4v*>(cp1 + co);
                const uint4v qc = *reinterpret_cast<const uint4v*>(cp2 + co);
                const uint4v qd = *reinterpret_cast<const uint4v*>(cp3 + co);

                const uint4* wk = wvp + (size_t)(kb0 + s * 4) * 256 + o0 + l15;
                FragU af[8];
                #pragma unroll
                for (int i = 0; i < 8; ++i) af[i].u = wk[i * 16];

                uint pr[4];
                #pragma unroll
                for (int j = 0; j < 4; ++j) {
                    f32x2 v = (f32x2){wg.x, wg.x} * unpk2(qa[j]);
                    v += (f32x2){wg.y, wg.y} * unpk2(qb[j]);
                    v += (f32x2){wg.z, wg.z} * unpk2(qc[j]);
                    v += (f32x2){wg.w, wg.w} * unpk2(qd[j]);
                    uint r;
                    asm("v_cvt_pk_bf16_f32 %0, %1, %2"
                        : "=v"(r) : "v"(v.x), "v"(v.y));
                    pr[j] = r;
                }
                FragU bfrag;
                bfrag.u = make_uint4(pr[0], pr[1], pr[2], pr[3]);

                #pragma unroll
                for (int i = 0; i < 8; ++i)
                    acc[i] = __builtin_amdgcn_mfma_f32_16x16x32_bf16(
                        af[i].h, bfrag.h, acc[i], 0, 0, 0);
            }
        }
    }

    float* ob = out + (size_t)b * On * PB;
    #pragma unroll
    for (int i = 0; i < 8; ++i)
        #pragma unroll
        for (int j = 0; j < 4; ++j)
            ob[((size_t)(o0 + i * 16 + g * 4 + j)) * PB + p0 + p] = acc[i][j];
}

// ---------------------------------------------------------------- launch
extern "C" void kernel_launch(void* const* d_in, const int* in_sizes, int n_in,
                              void* d_out, int out_size, void* d_ws, size_t ws_size,
                              hipStream_t stream)
{
    const float* x    = (const float*)d_in[0];
    const float* offw = (const float*)d_in[1];
    const float* offb = (const float*)d_in[2];
    const float* modw = (const float*)d_in[3];
    const float* modb = (const float*)d_in[4];
    const float* wgt  = (const float*)d_in[5];
    float* out = (float*)d_out;

    char* ws = (char*)d_ws;
    float*  offm = (float*)ws;                   // 1,769,472 B
    ushort* wTb  = (ushort*)(ws + 1769472);      // 1,179,648 B
    ushort* owh  = (ushort*)(ws + 2949120);      // 147,456 B
    ushort* owl  = (ushort*)(ws + 3096576);      // 147,456 B
    ushort* xbf  = (ushort*)(ws + 3244032);      // 8,388,608 B
    ushort* xlr  = (ushort*)(ws + 11632640);     // 8,388,608 B -> 20.0 MB total

    nhwcpack_kernel<<<dim3(512), dim3(256), 0, stream>>>(
        x, wgt, offw, modw, xbf, xlr, wTb, owh, owl);
    offmask_mfma_kernel<<<dim3(256), dim3(512), 0, stream>>>(
        xbf, xlr, offb, modb, owh, owl, offm);
    deform_reg_kernel<<<dim3(256), dim3(512), 0, stream>>>(
        xbf, offm, wTb, out);
}

// Round 7
// 67.688 us; speedup vs baseline: 2.7295x; 2.7295x over previous
//
#include <hip/hip_runtime.h>
#include <math.h>

// Modulated deformable conv v2: B=4, C=256, H=W=64, O=256, K=3, PAD=1
// r24b: FP16 UNIFICATION (r24 with compile fix: cvt_pkrtz returns a
//       __fp16 ext-vector; bit_cast it instead of implicit init).
//  - K1: single fp16 NHWC plane xhf (drops bf16-lo plane entirely) + fp16
//        weight packs. fp16 (2^-11) beats bf16-hi (2^-8) everywhere.
//  - K2: r13 structure, single-plane fp16: half the gathers, 1/3 the MFMAs,
//        half the LDS.
//  - K3: r18 structure VERBATIM (fastest measured: 41.4us) with fp16
//        combine (v_cvt_pkrtz pack) + f16 MFMA.

constexpr int Bn = 4;
constexpr int Cn = 256;
constexpr int Hn = 64;
constexpr int Wn = 64;
constexpr int On = 256;
constexpr int PB = Hn * Wn;     // 4096
constexpr int NCH = 27;

typedef __attribute__((ext_vector_type(8))) _Float16 f16x8;  // 4 VGPRs
typedef __attribute__((ext_vector_type(4))) float f32x4;

union FragU { uint4 u; f16x8 h; };

__device__ inline ushort f2h(float f) {
    _Float16 h = (_Float16)f;
    return __builtin_bit_cast(ushort, h);
}
__device__ inline float hlo(uint u) {
    _Float16 h = __builtin_bit_cast(_Float16, (ushort)(u & 0xffffu));
    return (float)h;
}
__device__ inline float hhi(uint u) {
    _Float16 h = __builtin_bit_cast(_Float16, (ushort)(u >> 16));
    return (float)h;
}
__device__ inline uint pkh(float a, float b) {
    return __builtin_bit_cast(uint, __builtin_amdgcn_cvt_pkrtz(a, b));
}

// ---------------------------------------------------------------- kernel 1
// NCHW fp32 -> NHWC fp16 plane + fp16 weight packs (r16/r17 frame, lo-plane
// deleted).
__global__ __launch_bounds__(256)
void nhwcpack_kernel(const float* __restrict__ x,
                     const float* __restrict__ w,
                     const float* __restrict__ offw,
                     const float* __restrict__ modw,
                     ushort* __restrict__ xhf,
                     ushort* __restrict__ wTb,
                     ushort* __restrict__ owf)
{
    const int bid = blockIdx.x;
    const int b = bid >> 7, seg = bid & 127;
    const int t = threadIdx.x;
    __shared__ float tile[32][257];

    const float* src = x + (size_t)b * Cn * PB + seg * 32;
    #pragma unroll 4
    for (int i = 0; i < 32; ++i) {
        const int idx = i * 256 + t;
        const int c = idx >> 5, p = idx & 31;
        tile[p][c] = src[(size_t)c * PB + p];
    }
    __syncthreads();

    const int pr = t & 127;
    const int r0 = (t >> 7) * 16;
    uint* dH = reinterpret_cast<uint*>(xhf + ((size_t)b * PB + seg * 32) * 256);
    #pragma unroll 4
    for (int i = 0; i < 16; ++i) {
        const int row = r0 + i;
        const float v0 = tile[row][2 * pr];
        const float v1 = tile[row][2 * pr + 1];
        dH[(size_t)row * 128 + pr] = pkh(v0, v1);
    }

    #pragma unroll 1
    for (int u = 0; u < 5; ++u) {
        int unit = (u < 4) ? bid * 4 + u : (bid < 256 ? 2048 + bid : -1);
        if (unit < 0) break;
        const int tap = unit >> 8, c = unit & 255;
        const int o = t;
        wTb[((size_t)(unit >> 3) * 256 + o) * 8 + (c & 7)] =
            f2h(w[((size_t)o * Cn + c) * 9 + tap]);
        if (o < 32) {
            float v = 0.f;
            if (o < 18)      v = offw[((size_t)o * Cn + c) * 9 + tap];
            else if (o < 27) v = modw[((size_t)(o - 18) * Cn + c) * 9 + tap];
            owf[((size_t)(unit >> 3) * 32 + o) * 8 + (c & 7)] = f2h(v);
        }
    }
}

// ---------------------------------------------------------------- kernel 2
// offset/mask conv, r13 structure, single fp16 plane: half gathers, one
// MFMA per s (was 3), colsH only (32 KB).
__global__ __launch_bounds__(512, 2)
void offmask_mfma_kernel(const ushort* __restrict__ xhf,
                         const float* __restrict__ offb,
                         const float* __restrict__ modb,
                         const ushort* __restrict__ owf,
                         float* __restrict__ offm)
{
    const int hw = blockIdx.x;
    const int blk = (hw & 7) * 32 + (hw >> 3);
    const int b = blk >> 6, row = blk & 63;
    const int t = threadIdx.x;
    const int lane = t & 63;
    const int wv  = t >> 6;
    const int l15 = lane & 15;
    const int g   = lane >> 4;
    const int mt  = wv >> 2;
    const int nt  = wv & 3;

    __shared__ uint colsH[8][1024];   // 32 KB

    const ushort* xhb = xhf + (size_t)b * PB * 256;
    const int posT0 = t >> 4;
    const int chq   = t & 15;

    const int ws0 = posT0 * 16
        + 4 * ((chq >> 2) ^ (posT0 & 3) ^ ((posT0 >> 2) & 3)) + (chq & 3);
    const int posT1 = posT0 + 32;
    const int ws1 = posT1 * 16
        + 4 * ((chq >> 2) ^ (posT1 & 3) ^ ((posT1 >> 2) & 3)) + (chq & 3);

    const uint4* owfV = reinterpret_cast<const uint4*>(owf);

    f32x4 acc = (f32x4){0.f, 0.f, 0.f, 0.f};
    const int p = nt * 16 + l15;
    const int ridx = p * 4 + (g ^ (p & 3) ^ ((p >> 2) & 3));

    #pragma unroll 1
    for (int tap = 0; tap < 9; ++tap) {
        const int ty = tap / 3, tx = tap % 3;
        const int y = row - 1 + ty;
        const int xc0 = posT0 - 1 + tx;
        const int xc1 = posT1 - 1 + tx;
        const bool ok0 = (y >= 0) && (y < Hn) && (xc0 >= 0) && (xc0 < Wn);
        const bool ok1 = (y >= 0) && (y < Hn) && (xc1 >= 0) && (xc1 < Wn);
        const int ya  = max(y, 0);
        const int xa0 = min(max(xc0, 0), Wn - 1);
        const int xa1 = min(max(xc1, 0), Wn - 1);
        const size_t p0b = ((size_t)(ya * Wn + xa0)) * 256 + 2 * chq;
        const size_t p1b = ((size_t)(ya * Wn + xa1)) * 256 + 2 * chq;

        uint h0[8], h1[8];
        #pragma unroll
        for (int s = 0; s < 8; ++s) {
            h0[s] = h1[s] = 0u;
            if (ok0) h0[s] = *reinterpret_cast<const uint*>(xhb + p0b + s * 32);
            if (ok1) h1[s] = *reinterpret_cast<const uint*>(xhb + p1b + s * 32);
        }
        uint4 aH[8];
        #pragma unroll
        for (int s = 0; s < 8; ++s) {
            const size_t kb = (size_t)((tap * 8 + s) * 4 + g) * 32 + mt * 16 + l15;
            aH[s] = owfV[kb];
        }

        __syncthreads();

        #pragma unroll
        for (int s = 0; s < 8; ++s) {
            colsH[s][ws0] = h0[s];
            colsH[s][ws1] = h1[s];
        }
        __syncthreads();

        #pragma unroll
        for (int s = 0; s < 8; ++s) {
            FragU aHH, bH;
            aHH.u = aH[s];
            bH.u = reinterpret_cast<const uint4*>(colsH[s])[ridx];
            acc = __builtin_amdgcn_mfma_f32_16x16x32_f16(aHH.h, bH.h, acc, 0, 0, 0);
        }
    }

    const int pos = nt * 16 + l15;
    #pragma unroll
    for (int j = 0; j < 4; ++j) {
        const int ch = mt * 16 + g * 4 + j;
        if (ch < NCH) {
            float v = acc[j];
            if (ch < 18) v += offb[ch];
            else         v = 2.f / (1.f + expf(-(v + modb[ch - 18])));
            offm[((size_t)(b * NCH + ch)) * PB + row * 64 + pos] = v;
        }
    }
}

// ---------------------------------------------------------------- kernel 3
// r18 structure VERBATIM (fastest measured K3), fp16 data path. grid 256 =
// (b,row) XCD-swizzled. 512 threads = 8 waves; wave = M 32 x N 64.
__global__ __launch_bounds__(512, 2)
void deform_nhwc_kernel(const ushort* __restrict__ xhf,
                        const float* __restrict__ offm,
                        const ushort* __restrict__ wTb,
                        float* __restrict__ out)
{
    const int hw = blockIdx.x;
    const int blk = (hw & 7) * 32 + (hw >> 3);   // XCD swizzle (256 = 8*32)
    const int b = blk >> 6, row = blk & 63;
    const int p0 = row * 64;
    const int t = threadIdx.x;
    const int lane = t & 63;
    const int wv  = t >> 6;
    const int l15 = lane & 15;
    const int g   = lane >> 4;

    __shared__ int4   s_off[576];        // [tap][pos 0..63]
    __shared__ float4 s_wgt[576];
    __shared__ uint   cols[4][1024];     // [step][pos*16+slot] (16 KB)

    for (int ti = t; ti < 576; ti += 512) {
        const int k = ti >> 6, pos = ti & 63;
        const int p = p0 + pos;
        const float dy = offm[((size_t)(b * NCH + 2 * k)) * PB + p];
        const float dx = offm[((size_t)(b * NCH + 2 * k + 1)) * PB + p];
        const float m  = offm[((size_t)(b * NCH + 18 + k)) * PB + p];
        const int ky = k / 3, kx = k % 3;
        const float py = dy + (float)(ky + row - 1);
        const float px = dx + (float)(kx + pos - 1);
        const float y0f = floorf(py), x0f = floorf(px);
        const float fy = py - y0f, fx = px - x0f;
        const int y0 = (int)y0f, x0i = (int)x0f;
        const int y1 = y0 + 1, x1 = x0i + 1;
        const bool vy0 = (y0 >= 0) && (y0 < Hn);
        const bool vy1 = (y1 >= 0) && (y1 < Hn);
        const bool vx0 = (x0i >= 0) && (x0i < Wn);
        const bool vx1 = (x1 >= 0) && (x1 < Wn);
        const int y0c = min(max(y0, 0), Hn - 1);
        const int y1c = min(max(y1, 0), Hn - 1);
        const int x0c = min(max(x0i, 0), Wn - 1);
        const int x1c = min(max(x1, 0), Wn - 1);
        s_off[ti] = make_int4(y0c * Wn + x0c, y0c * Wn + x1c,
                              y1c * Wn + x0c, y1c * Wn + x1c);
        s_wgt[ti] = make_float4(
            (vy0 && vx0) ? (1.f - fy) * (1.f - fx) * m : 0.f,
            (vy0 && vx1) ? (1.f - fy) * fx * m : 0.f,
            (vy1 && vx0) ? fy * (1.f - fx) * m : 0.f,
            (vy1 && vx1) ? fy * fx * m : 0.f);
    }
    __syncthreads();   // tap tables visible before ANY gather

    const ushort* xb = xhf + (size_t)b * PB * 256;
    const int posT = t >> 4;       // 0..31; this thread stages posT and posT+32
    const int chq  = t & 15;
    const uint4* wvp = reinterpret_cast<const uint4*>(wTb);
    const int o0 = wv * 32;

    const int ws0 = posT * 16
        + 4 * ((chq >> 2) ^ (posT & 3) ^ ((posT >> 2) & 3)) + (chq & 3);
    // posT+32: low bits of pos identical -> slot = ws0 + 512

    int ri[4];
    #pragma unroll
    for (int nt = 0; nt < 4; ++nt) {
        const int p = nt * 16 + l15;
        ri[nt] = p * 4 + (g ^ (p & 3) ^ ((p >> 2) & 3));
    }

    f32x4 acc[2][4];
    #pragma unroll
    for (int ot = 0; ot < 2; ++ot)
        #pragma unroll
        for (int nt = 0; nt < 4; ++nt)
            acc[ot][nt] = (f32x4){0.f, 0.f, 0.f, 0.f};

    #pragma unroll 1
    for (int cch = 0; cch < 18; ++cch) {
        const int tap = cch >> 1, cc0 = (cch & 1) * 128;
        const int4   offA = s_off[tap * 64 + posT];
        const float4 wgtA = s_wgt[tap * 64 + posT];
        const int4   offB = s_off[tap * 64 + posT + 32];
        const float4 wgtB = s_wgt[tap * 64 + posT + 32];
        const ushort* xc = xb + cc0 + 2 * chq;

        // ---- issue 32 fp16 gathers (2 pos x 4 corners x 4 steps) + 8 A-loads
        uint qa[4], qb[4], qc[4], qd[4], ra[4], rb[4], rc[4], rd[4];
        #pragma unroll
        for (int s = 0; s < 4; ++s) {
            const int so = s * 32;
            qa[s] = *reinterpret_cast<const uint*>(xc + (size_t)offA.x * 256 + so);
            qb[s] = *reinterpret_cast<const uint*>(xc + (size_t)offA.y * 256 + so);
            qc[s] = *reinterpret_cast<const uint*>(xc + (size_t)offA.z * 256 + so);
            qd[s] = *reinterpret_cast<const uint*>(xc + (size_t)offA.w * 256 + so);
            ra[s] = *reinterpret_cast<const uint*>(xc + (size_t)offB.x * 256 + so);
            rb[s] = *reinterpret_cast<const uint*>(xc + (size_t)offB.y * 256 + so);
            rc[s] = *reinterpret_cast<const uint*>(xc + (size_t)offB.z * 256 + so);
            rd[s] = *reinterpret_cast<const uint*>(xc + (size_t)offB.w * 256 + so);
        }
        uint4 apre[4][2];
        #pragma unroll
        for (int s = 0; s < 4; ++s) {
            const int kb = (cch * 4 + s) * 4 + g;
            apre[s][0] = wvp[(size_t)kb * 256 + o0 + l15];
            apre[s][1] = wvp[(size_t)kb * 256 + o0 + 16 + l15];
        }

        __syncthreads();   // prior chunk's MFMA reads complete before overwrite

        #pragma unroll
        for (int s = 0; s < 4; ++s) {
            const float v0 = wgtA.x * hlo(qa[s]) + wgtA.y * hlo(qb[s])
                           + wgtA.z * hlo(qc[s]) + wgtA.w * hlo(qd[s]);
            const float v1 = wgtA.x * hhi(qa[s]) + wgtA.y * hhi(qb[s])
                           + wgtA.z * hhi(qc[s]) + wgtA.w * hhi(qd[s]);
            cols[s][ws0] = pkh(v0, v1);
            const float u0 = wgtB.x * hlo(ra[s]) + wgtB.y * hlo(rb[s])
                           + wgtB.z * hlo(rc[s]) + wgtB.w * hlo(rd[s]);
            const float u1 = wgtB.x * hhi(ra[s]) + wgtB.y * hhi(rb[s])
                           + wgtB.z * hhi(rc[s]) + wgtB.w * hhi(rd[s]);
            cols[s][ws0 + 512] = pkh(u0, u1);
        }
        __syncthreads();   // writes visible before MFMA reads

        #pragma unroll
        for (int s = 0; s < 4; ++s) {
            FragU a0, a1, bf[4];
            a0.u = apre[s][0]; a1.u = apre[s][1];
            #pragma unroll
            for (int nt = 0; nt < 4; ++nt)
                bf[nt].u = reinterpret_cast<const uint4*>(cols[s])[ri[nt]];
            #pragma unroll
            for (int nt = 0; nt < 4; ++nt) {
                acc[0][nt] = __builtin_amdgcn_mfma_f32_16x16x32_f16(
                    a0.h, bf[nt].h, acc[0][nt], 0, 0, 0);
                acc[1][nt] = __builtin_amdgcn_mfma_f32_16x16x32_f16(
                    a1.h, bf[nt].h, acc[1][nt], 0, 0, 0);
            }
        }
    }

    float* ob = out + (size_t)b * On * PB;
    #pragma unroll
    for (int ot = 0; ot < 2; ++ot)
        #pragma unroll
        for (int nt = 0; nt < 4; ++nt)
            #pragma unroll
            for (int j = 0; j < 4; ++j)
                ob[((size_t)(o0 + ot * 16 + g * 4 + j)) * PB
                   + p0 + nt * 16 + l15] = acc[ot][nt][j];
}

// ---------------------------------------------------------------- launch
extern "C" void kernel_launch(void* const* d_in, const int* in_sizes, int n_in,
                              void* d_out, int out_size, void* d_ws, size_t ws_size,
                              hipStream_t stream)
{
    const float* x    = (const float*)d_in[0];
    const float* offw = (const float*)d_in[1];
    const float* offb = (const float*)d_in[2];
    const float* modw = (const float*)d_in[3];
    const float* modb = (const float*)d_in[4];
    const float* wgt  = (const float*)d_in[5];
    float* out = (float*)d_out;

    char* ws = (char*)d_ws;
    float*  offm = (float*)ws;                   // 1,769,472 B
    ushort* wTb  = (ushort*)(ws + 1769472);      // 1,179,648 B
    ushort* owf  = (ushort*)(ws + 2949120);      // 147,456 B
    // region at +3096576 (was owl) now unused
    ushort* xhf  = (ushort*)(ws + 3244032);      // 8,388,608 B (fp16 NHWC)
    // region at +11632640 (was xlr) now unused

    nhwcpack_kernel<<<dim3(512), dim3(256), 0, stream>>>(
        x, wgt, offw, modw, xhf, wTb, owf);
    offmask_mfma_kernel<<<dim3(256), dim3(512), 0, stream>>>(
        xhf, offb, modb, owf, offm);
    deform_nhwc_kernel<<<dim3(256), dim3(512), 0, stream>>>(
        xhf, offm, wTb, out);
}